// Round 3
// baseline (669.193 us; speedup 1.0000x reference)
//
#include <hip/hip_runtime.h>

// Balanced sinkhorn, persistent kernel, round 8.
// R7 post-mortem: 13.3us/allreduce. Stage-1 column value-poll was
// UNCOALESCED (each wave polls 64 distinct 2KB-strided lines): 65536
// agent-scope load requests per global poll round flood the L3/coherence
// point, inflating publish tails and both detect hops. R6/R7 lesson:
// the scarce resource is L3 REQUEST slots, not bytes.
// R8: transpose the publish so all polling is coalesced:
//   1. publisher b scatter-stores partial[k] to P[par][k][b]
//      (256 one-shot 8B stores; issue ~0.4us, absorbed in fan-in tail)
//   2. owner k value-polls its own contiguous row P[par][k][0..255]
//      (2KB, 8 lines/wave-request, lines exclusive to this owner)
//   3. restore NaN, wave+LDS reduce (same summation order as R7 ->
//      bit-identical), result replicated x16 into per-phase res[48][16][256]
//   4. consumers value-poll res[ph][bid&15][t] (coalesced, unchanged)
// Sentinel-restore ordering unchanged (R5-validated): restore vmcnt-acked at
// __syncthreads() before res store; any ph+2 republish transitively depends
// on consuming res[ph].
// Phase math / LDS tiles / replicated optimizer identical to R3-R7
// (validated, absmax 2.4e-4).

namespace {

constexpr int KDIM = 256;
constexpr int NBLK = 256;   // 1 block/CU, all co-resident (LDS-forced)
constexpr int ROWS = 64;    // rows per block
constexpr int NREP = 16;    // result replicas (16 blocks/line fan-in)
constexpr int NPH  = 48;    // 1 + 9*5 + 2 allreduce phases
constexpr float L2E20 = 28.853900817779268f;  // 20 * log2(e)

// ws layout (doubles):
//   P[2][256 k][256 blk]         131072 dbl (1 MB), parity-reused, owner-restored
//   res[48 ph][16 rep][256 k]    196608 dbl (1.5 MB), per-phase fresh
constexpr size_t P_DBL   = 2ull * KDIM * NBLK;          // 131072
constexpr size_t RES_OFF = P_DBL;
constexpr size_t RES_DBL = (size_t)NPH * NREP * KDIM;   // 196608
constexpr size_t WS_DBL  = P_DBL + RES_DBL;             // 327680 (2.62 MB)

__device__ __forceinline__ double fast_exp_d(double x) {
  const double LOG2E  = 1.4426950408889634074;
  const double LN2_HI = 6.93147180369123816490e-01;
  const double LN2_LO = 1.90821492927058770002e-10;
  double n = rint(x * LOG2E);
  double t = fma(-n, LN2_HI, x);
  t = fma(-n, LN2_LO, t);
  double p = 2.4801587301587302e-05;
  p = fma(p, t, 1.9841269841269841e-04);
  p = fma(p, t, 1.3888888888888889e-03);
  p = fma(p, t, 8.3333333333333333e-03);
  p = fma(p, t, 4.1666666666666664e-02);
  p = fma(p, t, 1.6666666666666666e-01);
  p = fma(p, t, 0.5);
  p = fma(p, t, 1.0);
  p = fma(p, t, 1.0);
  long long ni = (long long)n;
  double s = __longlong_as_double((unsigned long long)(ni + 1023LL) << 52);
  return p * s;
}

__device__ __forceinline__ double wave_sum_d(double v) {
#pragma unroll
  for (int o = 32; o > 0; o >>= 1) v += __shfl_down(v, o);
  return v;
}
__device__ __forceinline__ double wave_max_d(double v) {
#pragma unroll
  for (int o = 32; o > 0; o >>= 1) v = fmax(v, __shfl_down(v, o));
  return v;
}

__device__ __forceinline__ double pload(const double* p) {
  return __hip_atomic_load(p, __ATOMIC_RELAXED, __HIP_MEMORY_SCOPE_AGENT);
}
__device__ __forceinline__ void pstore(double* p, double v) {
  __hip_atomic_store(p, v, __ATOMIC_RELAXED, __HIP_MEMORY_SCOPE_AGENT);
}

}  // namespace

// ---------------------------------------------------------------------------
__global__ __launch_bounds__(256) void kInitWS(double* __restrict__ ws) {
  const double QN = __builtin_nan("");
  size_t gid = (size_t)blockIdx.x * 256 + threadIdx.x;
  size_t stride = (size_t)gridDim.x * 256;
  for (size_t j = gid; j < WS_DBL; j += stride) ws[j] = QN;
}

// ---------------------------------------------------------------------------
__global__ __launch_bounds__(256, 1) void sink_main(
    const float* __restrict__ feat, const float* __restrict__ w_in,
    float* __restrict__ out, double* __restrict__ ws) {
  __shared__ float  Et[ROWS * KDIM];   // 64 KB
  __shared__ float  Ft[ROWS * KDIM];   // 64 KB
  __shared__ double alpha[KDIM];
  __shared__ double v1s[ROWS], v2s[ROWS], v3s[ROWS];
  __shared__ double grow[ROWS], wrow[ROWS], sbr[ROWS];
  __shared__ float  mrow[ROWS];
  __shared__ double sred[8];

  const int t = threadIdx.x, bid = blockIdx.x;
  const int wv = t >> 6, lane = t & 63;
  const int b0 = bid * ROWS;
  const double QN = __builtin_nan("");

  double* P   = ws;
  double* res = ws + RES_OFF;

  auto blk_sum = [&](double v) -> double {
    v = wave_sum_d(v);
    __syncthreads();
    if (lane == 0) sred[wv] = v;
    __syncthreads();
    return sred[0] + sred[1] + sred[2] + sred[3];
  };
  auto blk_max = [&](double v) -> double {
    v = wave_max_d(v);
    __syncthreads();
    if (lane == 0) sred[wv + 4] = v;
    __syncthreads();
    return fmax(fmax(sred[4], sred[5]), fmax(sred[6], sred[7]));
  };

  // ---- allreduce over blocks: thread t contributes pa for k=t,
  // returns the 256-block sum for k=t.
  auto allreduce = [&](unsigned ph, double pa) -> double {
    const int p = ph & 1;
    double* Pp = P + (size_t)p * KDIM * NBLK;
    // 1. publish transposed: value for k=t -> row k=t, slot bid (scatter)
    pstore(Pp + (size_t)t * NBLK + bid, pa);
    // 2. owner: this block owns k=bid; poll own CONTIGUOUS row (coalesced)
    double* e = Pp + (size_t)bid * NBLK + t;   // slot for publisher b=t
    double v;
    for (;;) {
      v = pload(e);
      if (!__builtin_isnan(v)) break;
      __builtin_amdgcn_s_sleep(2);
    }
    pstore(e, QN);  // restore sentinel for phase ph+2 (same parity)
    v = wave_sum_d(v);
    __syncthreads();  // vmcnt(0) drain: restores + publish ack'd at L3
    if (lane == 0) sred[wv] = v;
    __syncthreads();
    double s = sred[0] + sred[1] + sred[2] + sred[3];  // 256-block sum, k=bid
    // 3. replicate result x16 into the per-phase res slab
    if (t < NREP) pstore(res + ((size_t)ph * NREP + t) * KDIM + bid, s);
    // 4. consume own replica entry (coalesced 2KB per block)
    const double* re = res + ((size_t)ph * NREP + (bid & (NREP - 1))) * KDIM + t;
    double r;
    for (;;) {
      r = pload(re);
      if (!__builtin_isnan(r)) break;
      __builtin_amdgcn_s_sleep(2);
    }
    return r;
  };

  auto row_pass = [&](double* dstv) {
    double a0 = alpha[4 * lane + 0], a1 = alpha[4 * lane + 1];
    double a2 = alpha[4 * lane + 2], a3 = alpha[4 * lane + 3];
#pragma unroll 4
    for (int r = wv; r < ROWS; r += 4) {
      float4 e4 = ((const float4*)(Et + r * KDIM))[lane];
      double s1 = a0 * (double)e4.x + a1 * (double)e4.y +
                  a2 * (double)e4.z + a3 * (double)e4.w;
      s1 = wave_sum_d(s1);
      if (lane == 0) dstv[r] = s1;
    }
  };
  auto col_partial = [&]() -> double {
    double a = 0.0;
#pragma unroll 8
    for (int r = 0; r < ROWS; ++r) a += (double)Et[r * KDIM + t] * wrow[r];
    return a;
  };

  // ================= setup =================
  {
    const float4* src = (const float4*)(feat + (size_t)b0 * KDIM);
    float4* dst = (float4*)Ft;
#pragma unroll
    for (int s = 0; s < 16; ++s) dst[s * 256 + t] = src[s * 256 + t];
  }
  __syncthreads();
  for (int r = wv; r < ROWS; r += 4) {
    float4 f4 = ((const float4*)(Ft + r * KDIM))[lane];
    float m = fmaxf(fmaxf(f4.x, f4.y), fmaxf(f4.z, f4.w));
#pragma unroll
    for (int o = 32; o > 0; o >>= 1) m = fmaxf(m, __shfl_down(m, o));
    if (lane == 0) {
      mrow[r] = m;
      sbr[r] = fast_exp_d(20.0 * (double)m);
    }
  }
  __syncthreads();
  double pu0 = 0.0;
#pragma unroll 8
  for (int r = 0; r < ROWS; ++r) {
    float e = exp2f((Ft[r * KDIM + t] - mrow[r]) * L2E20);
    Et[r * KDIM + t] = e;
    pu0 += (double)e * sbr[r];
  }
  float w_t = w_in[t], buf_t = 0.0f;
  double k2_t;
  {
    double x = (double)w_t;
    double m = blk_max(x);
    double e = fast_exp_d(x - m);
    double s = blk_sum(e);
    k2_t = e / s;
  }
  unsigned ph = 0;
  double u0_t = allreduce(ph, pu0);

  // ================= outer loop =================
  for (int it = 0; it < 10; ++it) {
    double u1_t, u2_t;

    // ---- A: v1~, allreduce u1
    alpha[t] = k2_t / u0_t;
    __syncthreads();
    row_pass(v1s);
    __syncthreads();
    if (t < ROWS) wrow[t] = 1.0 / (16384.0 * v1s[t]);
    __syncthreads();
    {
      double pa = col_partial();
      ++ph; u1_t = allreduce(ph, pa);
    }

    // ---- B: v2~, allreduce u2
    alpha[t] = k2_t / u1_t;
    __syncthreads();
    row_pass(v2s);
    __syncthreads();
    if (t < ROWS) wrow[t] = 1.0 / (16384.0 * v2s[t]);
    __syncthreads();
    {
      double pa = col_partial();
      ++ph; u2_t = allreduce(ph, pa);
    }

    if (it == 9) {
      // ---- output: Q[b,k] = alpha3[k]*E~[r,k]/v3~[b]
      alpha[t] = k2_t / u2_t;
      __syncthreads();
      row_pass(v3s);
      __syncthreads();
      if (t < ROWS) wrow[t] = 1.0 / v3s[t];
      __syncthreads();
      double a3 = alpha[t];
#pragma unroll 4
      for (int r = 0; r < ROWS; ++r)
        out[(size_t)(b0 + r) * KDIM + t] =
            (float)(a3 * (double)Et[r * KDIM + t] * wrow[r]);
      return;
    }

    // ---- C: v3~, gv3~; allreduce gsum = (gdir + t3)  [only the sum is used]
    alpha[t] = k2_t / u2_t;
    __syncthreads();
    {
      double a0 = alpha[4 * lane + 0], a1 = alpha[4 * lane + 1];
      double a2 = alpha[4 * lane + 2], a3 = alpha[4 * lane + 3];
#pragma unroll 2
      for (int r = wv; r < ROWS; r += 4) {
        float4 e4 = ((const float4*)(Et + r * KDIM))[lane];
        float4 f4 = ((const float4*)(Ft + r * KDIM))[lane];
        double p0 = a0 * (double)e4.x, p1 = a1 * (double)e4.y;
        double p2 = a2 * (double)e4.z, p3 = a3 * (double)e4.w;
        double s1 = p0 + p1 + p2 + p3;
        double s2 = p0 * (double)f4.x + p1 * (double)f4.y +
                    p2 * (double)f4.z + p3 * (double)f4.w;
        s1 = wave_sum_d(s1);
        s2 = wave_sum_d(s2);
        if (lane == 0) {
          v3s[r] = s1;
          grow[r] = s2 / (16384.0 * s1 * s1);  // gv3~
        }
      }
    }
    __syncthreads();
    if (t < ROWS) wrow[t] = -1.0 / (16384.0 * v3s[t]);
    __syncthreads();
    double gsum_t;
    {
      double ac1 = 0.0, ac2 = 0.0;
#pragma unroll 8
      for (int r = 0; r < ROWS; ++r) {
        double ed = (double)Et[r * KDIM + t];
        ac1 += ed * (double)Ft[r * KDIM + t] * wrow[r];
        ac2 += ed * grow[r];
      }
      ++ph; gsum_t = allreduce(ph, ac1 + ac2);
    }

    // ---- D: gu2 -> gv2~; allreduce ga2
    alpha[t] = -gsum_t * k2_t / (u2_t * u2_t);
    __syncthreads();
    row_pass(grow);
    __syncthreads();
    if (t < ROWS) wrow[t] = -grow[t] / (16384.0 * v2s[t] * v2s[t]);
    __syncthreads();
    double ga2_t;
    {
      double pa = col_partial();
      ++ph; ga2_t = allreduce(ph, pa);
    }

    // ---- E: gu1 -> gv1~; allreduce ga1
    alpha[t] = -ga2_t * k2_t / (u1_t * u1_t);
    __syncthreads();
    row_pass(grow);
    __syncthreads();
    if (t < ROWS) wrow[t] = -grow[t] / (16384.0 * v1s[t] * v1s[t]);
    __syncthreads();
    double ga1_t;
    {
      double pa = col_partial();
      ++ph; ga1_t = allreduce(ph, pa);
    }

    // ---- F: replicated optimizer step (block-local)
    {
      double gk2 = gsum_t / u2_t + ga2_t / u1_t + ga1_t / u0_t;
      double dot = blk_sum(k2_t * gk2);
      double gw = k2_t * (gk2 - dot) + 5.0 * (k2_t / 256.0 - 1.0 / 65536.0);
      double n2 = blk_sum(gw * gw);
      float normf = (float)sqrt(n2);
      float sc = fminf(1.0f, 1.0f / (normf + 1e-6f));
      float g = (float)gw * sc;
      buf_t = 0.99f * buf_t + g;
      w_t = w_t - 0.1f * buf_t;
      double x = (double)w_t;
      double m = blk_max(x);
      double e = fast_exp_d(x - m);
      double s = blk_sum(e);
      k2_t = e / s;
    }
  }
}

// ---------------------------------------------------------------------------
extern "C" void kernel_launch(void* const* d_in, const int* in_sizes, int n_in,
                              void* d_out, int out_size, void* d_ws,
                              size_t ws_size, hipStream_t stream) {
  (void)in_sizes; (void)n_in; (void)out_size; (void)ws_size;
  const float* feat = (const float*)d_in[0];
  const float* w_in = (const float*)d_in[1];
  float* out = (float*)d_out;
  double* ws = (double*)d_ws;

  kInitWS<<<128, 256, 0, stream>>>(ws);
  sink_main<<<NBLK, 256, 0, stream>>>(feat, w_in, out, ws);
}

// Round 5
// 611.702 us; speedup vs baseline: 1.0940x; 1.0940x over previous
//
#include <hip/hip_runtime.h>

// Balanced sinkhorn, persistent kernel, round 10.
// R9 post-mortem: failed (hang or compile) — it stacked three unproven
// primitives (XCC_ID discovery, plain-store/sc0-load intra-XCD coherence,
// sc0 asm spellings). Rule: one unproven primitive per round, with fallback.
// R10: tag-protocol hierarchical allreduce using ONLY R5-R8-proven
// primitives (agent-relaxed pstore/pload, vmcnt-drain+syncthreads, s_sleep
// value polls). Structure per phase (48 serial phases):
//   - 8 groups x 32 blocks (grp=bid>>5, rank=bid&31)
//   - member: publish 2KB value row ONCE -> drain -> publish 8B tag=ph
//     (monotonic tag: no ABA, no sentinel restores, parity-2 value reuse)
//   - owner (rank 0): poll 31 member tags (4 LINES, not 992) -> one-shot
//     batched read of 31 rows (relaxed atomic loads pipeline; waits only
//     before use) -> publish group-sum row + tag
//   - ALL blocks: poll 8 group tags (8 lines) -> read 8 group rows ->
//     identical ascending local sum. (R9's broadcast hop deleted.)
// Poll flood drops ~30x vs R8 (tags only); data regions read exactly once.
// The 8-wide exchange is a de-facto global barrier each phase => no block
// leads another by >1 phase => parity-2 slab reuse is race-free.
// Phase math / LDS tiles / replicated optimizer identical to R3-R8
// (validated, absmax 2.4e-4; only fp64 summation association changes).

namespace {

constexpr int KDIM = 256;
constexpr int NBLK = 256;   // 1 block/CU, all co-resident (LDS-forced)
constexpr int ROWS = 64;    // rows per block
constexpr int NGRP = 8;     // groups
constexpr int GSZ  = 32;    // blocks per group
constexpr float L2E20 = 28.853900817779268f;  // 20 * log2(e)

// ws layout (doubles):
//   S1V[2][8][32][256]  131072  member value rows (parity-reused, tag-gated)
//   S1T[2][8][32]          512  member tags (= phase number as double)
//   S2V[2][8][256]        4096  group-sum rows
//   S2T[2][8][8]           128  group tags (one 64B line each)
constexpr size_t S1V_OFF = 0;
constexpr size_t S1T_OFF = 131072;
constexpr size_t S2V_OFF = 131584;
constexpr size_t S2T_OFF = 135680;
constexpr size_t WS_DBL  = 135808;   // ~1.09 MB

__device__ __forceinline__ double fast_exp_d(double x) {
  const double LOG2E  = 1.4426950408889634074;
  const double LN2_HI = 6.93147180369123816490e-01;
  const double LN2_LO = 1.90821492927058770002e-10;
  double n = rint(x * LOG2E);
  double t = fma(-n, LN2_HI, x);
  t = fma(-n, LN2_LO, t);
  double p = 2.4801587301587302e-05;
  p = fma(p, t, 1.9841269841269841e-04);
  p = fma(p, t, 1.3888888888888889e-03);
  p = fma(p, t, 8.3333333333333333e-03);
  p = fma(p, t, 4.1666666666666664e-02);
  p = fma(p, t, 1.6666666666666666e-01);
  p = fma(p, t, 0.5);
  p = fma(p, t, 1.0);
  p = fma(p, t, 1.0);
  long long ni = (long long)n;
  double s = __longlong_as_double((unsigned long long)(ni + 1023LL) << 52);
  return p * s;
}

__device__ __forceinline__ double wave_sum_d(double v) {
#pragma unroll
  for (int o = 32; o > 0; o >>= 1) v += __shfl_down(v, o);
  return v;
}
__device__ __forceinline__ double wave_max_d(double v) {
#pragma unroll
  for (int o = 32; o > 0; o >>= 1) v = fmax(v, __shfl_down(v, o));
  return v;
}

__device__ __forceinline__ double pload(const double* p) {
  return __hip_atomic_load(p, __ATOMIC_RELAXED, __HIP_MEMORY_SCOPE_AGENT);
}
__device__ __forceinline__ void pstore(double* p, double v) {
  __hip_atomic_store(p, v, __ATOMIC_RELAXED, __HIP_MEMORY_SCOPE_AGENT);
}

}  // namespace

// ---------------------------------------------------------------------------
__global__ __launch_bounds__(256) void kInitWS(double* __restrict__ ws) {
  const double QN = __builtin_nan("");
  size_t gid = (size_t)blockIdx.x * 256 + threadIdx.x;
  size_t stride = (size_t)gridDim.x * 256;
  for (size_t j = gid; j < WS_DBL; j += stride) ws[j] = QN;
}

// ---------------------------------------------------------------------------
__global__ __launch_bounds__(256, 1) void sink_main(
    const float* __restrict__ feat, const float* __restrict__ w_in,
    float* __restrict__ out, double* __restrict__ ws) {
  __shared__ float  Et[ROWS * KDIM];   // 64 KB
  __shared__ float  Ft[ROWS * KDIM];   // 64 KB
  __shared__ double alpha[KDIM];
  __shared__ double v1s[ROWS], v2s[ROWS], v3s[ROWS];
  __shared__ double grow[ROWS], wrow[ROWS], sbr[ROWS];
  __shared__ float  mrow[ROWS];
  __shared__ double sred[8];

  const int t = threadIdx.x, bid = blockIdx.x;
  const int wv = t >> 6, lane = t & 63;
  const int b0 = bid * ROWS;
  const int grp = bid >> 5, rank = bid & 31;

  double* S1V = ws + S1V_OFF;
  double* S1T = ws + S1T_OFF;
  double* S2V = ws + S2V_OFF;
  double* S2T = ws + S2T_OFF;

  auto blk_sum = [&](double v) -> double {
    v = wave_sum_d(v);
    __syncthreads();
    if (lane == 0) sred[wv] = v;
    __syncthreads();
    return sred[0] + sred[1] + sred[2] + sred[3];
  };
  auto blk_max = [&](double v) -> double {
    v = wave_max_d(v);
    __syncthreads();
    if (lane == 0) sred[wv + 4] = v;
    __syncthreads();
    return fmax(fmax(sred[4], sred[5]), fmax(sred[6], sred[7]));
  };

  // ---- allreduce over blocks: thread t contributes pa for k=t,
  // returns the 256-block sum for k=t.
  auto allreduce = [&](unsigned ph, double pa) -> double {
    const int par = (int)(ph & 1);
    const double dph = (double)ph;
    if (rank == 0) {
      // ===== owner: poll member tags (4 lines), gather, publish group sum
      if (t >= 1 && t < GSZ) {
        const double* tp = S1T + ((size_t)par * NGRP + grp) * GSZ + t;
        while (pload(tp) != dph) __builtin_amdgcn_s_sleep(1);
      }
      __syncthreads();
      double acc = pa;
      {
        const double* B = S1V + (((size_t)par * NGRP + grp) * GSZ) * KDIM + t;
#pragma unroll
        for (int g = 0; g < 3; ++g) {
          const double* r0 = B + (size_t)(1 + 8 * g) * KDIM;
          double w0 = pload(r0 + 0 * KDIM), w1 = pload(r0 + 1 * KDIM);
          double w2 = pload(r0 + 2 * KDIM), w3 = pload(r0 + 3 * KDIM);
          double w4 = pload(r0 + 4 * KDIM), w5 = pload(r0 + 5 * KDIM);
          double w6 = pload(r0 + 6 * KDIM), w7 = pload(r0 + 7 * KDIM);
          acc += w0; acc += w1; acc += w2; acc += w3;
          acc += w4; acc += w5; acc += w6; acc += w7;
        }
        const double* r0 = B + (size_t)25 * KDIM;   // rows 25..31
        double w0 = pload(r0 + 0 * KDIM), w1 = pload(r0 + 1 * KDIM);
        double w2 = pload(r0 + 2 * KDIM), w3 = pload(r0 + 3 * KDIM);
        double w4 = pload(r0 + 4 * KDIM), w5 = pload(r0 + 5 * KDIM);
        double w6 = pload(r0 + 6 * KDIM);
        acc += w0; acc += w1; acc += w2; acc += w3;
        acc += w4; acc += w5; acc += w6;
      }
      pstore(S2V + ((size_t)par * NGRP + grp) * KDIM + t, acc);
      asm volatile("s_waitcnt vmcnt(0)" ::: "memory");
      __syncthreads();  // all threads' group-sum stores ack'd at L3
      if (t == 0) pstore(S2T + ((size_t)par * NGRP + grp) * 8, dph);
    } else {
      // ===== member: publish value row once, drain, publish tag
      pstore(S1V + (((size_t)par * NGRP + grp) * GSZ + rank) * KDIM + t, pa);
      asm volatile("s_waitcnt vmcnt(0)" ::: "memory");
      __syncthreads();  // all threads' value stores ack'd at L3
      if (t == 0) pstore(S1T + ((size_t)par * NGRP + grp) * GSZ + rank, dph);
    }
    // ===== all blocks: poll 8 group tags (8 lines), then sum 8 group rows
    if (t < NGRP) {
      const double* sp = S2T + ((size_t)par * NGRP + t) * 8;
      while (pload(sp) != dph) __builtin_amdgcn_s_sleep(1);
    }
    __syncthreads();
    const double* V = S2V + (size_t)par * NGRP * KDIM + t;
    double x0 = pload(V + 0 * KDIM), x1 = pload(V + 1 * KDIM);
    double x2 = pload(V + 2 * KDIM), x3 = pload(V + 3 * KDIM);
    double x4 = pload(V + 4 * KDIM), x5 = pload(V + 5 * KDIM);
    double x6 = pload(V + 6 * KDIM), x7 = pload(V + 7 * KDIM);
    double tot = x0;
    tot += x1; tot += x2; tot += x3; tot += x4; tot += x5; tot += x6; tot += x7;
    return tot;
  };

  auto row_pass = [&](double* dstv) {
    double a0 = alpha[4 * lane + 0], a1 = alpha[4 * lane + 1];
    double a2 = alpha[4 * lane + 2], a3 = alpha[4 * lane + 3];
#pragma unroll 4
    for (int r = wv; r < ROWS; r += 4) {
      float4 e4 = ((const float4*)(Et + r * KDIM))[lane];
      double s1 = a0 * (double)e4.x + a1 * (double)e4.y +
                  a2 * (double)e4.z + a3 * (double)e4.w;
      s1 = wave_sum_d(s1);
      if (lane == 0) dstv[r] = s1;
    }
  };
  auto col_partial = [&]() -> double {
    double a = 0.0;
#pragma unroll 8
    for (int r = 0; r < ROWS; ++r) a += (double)Et[r * KDIM + t] * wrow[r];
    return a;
  };

  // ================= setup =================
  {
    const float4* src = (const float4*)(feat + (size_t)b0 * KDIM);
    float4* dst = (float4*)Ft;
#pragma unroll
    for (int s = 0; s < 16; ++s) dst[s * 256 + t] = src[s * 256 + t];
  }
  __syncthreads();
  for (int r = wv; r < ROWS; r += 4) {
    float4 f4 = ((const float4*)(Ft + r * KDIM))[lane];
    float m = fmaxf(fmaxf(f4.x, f4.y), fmaxf(f4.z, f4.w));
#pragma unroll
    for (int o = 32; o > 0; o >>= 1) m = fmaxf(m, __shfl_down(m, o));
    if (lane == 0) {
      mrow[r] = m;
      sbr[r] = fast_exp_d(20.0 * (double)m);
    }
  }
  __syncthreads();
  double pu0 = 0.0;
#pragma unroll 8
  for (int r = 0; r < ROWS; ++r) {
    float e = exp2f((Ft[r * KDIM + t] - mrow[r]) * L2E20);
    Et[r * KDIM + t] = e;
    pu0 += (double)e * sbr[r];
  }
  float w_t = w_in[t], buf_t = 0.0f;
  double k2_t;
  {
    double x = (double)w_t;
    double m = blk_max(x);
    double e = fast_exp_d(x - m);
    double s = blk_sum(e);
    k2_t = e / s;
  }
  unsigned ph = 0;
  double u0_t = allreduce(ph, pu0);

  // ================= outer loop =================
  for (int it = 0; it < 10; ++it) {
    double u1_t, u2_t;

    // ---- A: v1~, allreduce u1
    alpha[t] = k2_t / u0_t;
    __syncthreads();
    row_pass(v1s);
    __syncthreads();
    if (t < ROWS) wrow[t] = 1.0 / (16384.0 * v1s[t]);
    __syncthreads();
    {
      double pa = col_partial();
      ++ph; u1_t = allreduce(ph, pa);
    }

    // ---- B: v2~, allreduce u2
    alpha[t] = k2_t / u1_t;
    __syncthreads();
    row_pass(v2s);
    __syncthreads();
    if (t < ROWS) wrow[t] = 1.0 / (16384.0 * v2s[t]);
    __syncthreads();
    {
      double pa = col_partial();
      ++ph; u2_t = allreduce(ph, pa);
    }

    if (it == 9) {
      // ---- output: Q[b,k] = alpha3[k]*E~[r,k]/v3~[b]
      alpha[t] = k2_t / u2_t;
      __syncthreads();
      row_pass(v3s);
      __syncthreads();
      if (t < ROWS) wrow[t] = 1.0 / v3s[t];
      __syncthreads();
      double a3 = alpha[t];
#pragma unroll 4
      for (int r = 0; r < ROWS; ++r)
        out[(size_t)(b0 + r) * KDIM + t] =
            (float)(a3 * (double)Et[r * KDIM + t] * wrow[r]);
      return;
    }

    // ---- C: v3~, gv3~; allreduce gsum = (gdir + t3)  [only the sum is used]
    alpha[t] = k2_t / u2_t;
    __syncthreads();
    {
      double a0 = alpha[4 * lane + 0], a1 = alpha[4 * lane + 1];
      double a2 = alpha[4 * lane + 2], a3 = alpha[4 * lane + 3];
#pragma unroll 2
      for (int r = wv; r < ROWS; r += 4) {
        float4 e4 = ((const float4*)(Et + r * KDIM))[lane];
        float4 f4 = ((const float4*)(Ft + r * KDIM))[lane];
        double p0 = a0 * (double)e4.x, p1 = a1 * (double)e4.y;
        double p2 = a2 * (double)e4.z, p3 = a3 * (double)e4.w;
        double s1 = p0 + p1 + p2 + p3;
        double s2 = p0 * (double)f4.x + p1 * (double)f4.y +
                    p2 * (double)f4.z + p3 * (double)f4.w;
        s1 = wave_sum_d(s1);
        s2 = wave_sum_d(s2);
        if (lane == 0) {
          v3s[r] = s1;
          grow[r] = s2 / (16384.0 * s1 * s1);  // gv3~
        }
      }
    }
    __syncthreads();
    if (t < ROWS) wrow[t] = -1.0 / (16384.0 * v3s[t]);
    __syncthreads();
    double gsum_t;
    {
      double ac1 = 0.0, ac2 = 0.0;
#pragma unroll 8
      for (int r = 0; r < ROWS; ++r) {
        double ed = (double)Et[r * KDIM + t];
        ac1 += ed * (double)Ft[r * KDIM + t] * wrow[r];
        ac2 += ed * grow[r];
      }
      ++ph; gsum_t = allreduce(ph, ac1 + ac2);
    }

    // ---- D: gu2 -> gv2~; allreduce ga2
    alpha[t] = -gsum_t * k2_t / (u2_t * u2_t);
    __syncthreads();
    row_pass(grow);
    __syncthreads();
    if (t < ROWS) wrow[t] = -grow[t] / (16384.0 * v2s[t] * v2s[t]);
    __syncthreads();
    double ga2_t;
    {
      double pa = col_partial();
      ++ph; ga2_t = allreduce(ph, pa);
    }

    // ---- E: gu1 -> gv1~; allreduce ga1
    alpha[t] = -ga2_t * k2_t / (u1_t * u1_t);
    __syncthreads();
    row_pass(grow);
    __syncthreads();
    if (t < ROWS) wrow[t] = -grow[t] / (16384.0 * v1s[t] * v1s[t]);
    __syncthreads();
    double ga1_t;
    {
      double pa = col_partial();
      ++ph; ga1_t = allreduce(ph, pa);
    }

    // ---- F: replicated optimizer step (block-local)
    {
      double gk2 = gsum_t / u2_t + ga2_t / u1_t + ga1_t / u0_t;
      double dot = blk_sum(k2_t * gk2);
      double gw = k2_t * (gk2 - dot) + 5.0 * (k2_t / 256.0 - 1.0 / 65536.0);
      double n2 = blk_sum(gw * gw);
      float normf = (float)sqrt(n2);
      float sc = fminf(1.0f, 1.0f / (normf + 1e-6f));
      float g = (float)gw * sc;
      buf_t = 0.99f * buf_t + g;
      w_t = w_t - 0.1f * buf_t;
      double x = (double)w_t;
      double m = blk_max(x);
      double e = fast_exp_d(x - m);
      double s = blk_sum(e);
      k2_t = e / s;
    }
  }
}

// ---------------------------------------------------------------------------
extern "C" void kernel_launch(void* const* d_in, const int* in_sizes, int n_in,
                              void* d_out, int out_size, void* d_ws,
                              size_t ws_size, hipStream_t stream) {
  (void)in_sizes; (void)n_in; (void)out_size; (void)ws_size;
  const float* feat = (const float*)d_in[0];
  const float* w_in = (const float*)d_in[1];
  float* out = (float*)d_out;
  double* ws = (double*)d_ws;

  kInitWS<<<128, 256, 0, stream>>>(ws);
  sink_main<<<NBLK, 256, 0, stream>>>(feat, w_in, out, ws);
}